// Round 1
// baseline (161.994 us; speedup 1.0000x reference)
//
#include <hip/hip_runtime.h>
#include <stdint.h>

typedef __attribute__((ext_vector_type(8))) short short8;
typedef __attribute__((ext_vector_type(4))) float f32x4;
typedef __attribute__((ext_vector_type(4))) int i32x4;

#define SCALE_F 0.088388347648318447f   // 1/sqrt(128)

__device__ __forceinline__ unsigned short f2bf(float f) {
  union { float f; unsigned u; } v; v.f = f;
  unsigned r = v.u + 0x7fffu + ((v.u >> 16) & 1u);   // RNE
  return (unsigned short)(r >> 16);
}

// ---------------- kernel 0: fp32 -> bf16 convert (encodings + 3 weights) ----------------
__global__ __launch_bounds__(256) void cvt_kernel(
    const float* __restrict__ enc, const float* __restrict__ wq,
    const float* __restrict__ wk, const float* __restrict__ wv,
    unsigned short* __restrict__ enc_bf, unsigned short* __restrict__ w_bf) {
  const int encN4 = 4194304;  // 16777216/4
  const int wN4 = 32768;      // 131072/4
  int total = encN4 + 3 * wN4;
  for (int i = blockIdx.x * blockDim.x + threadIdx.x; i < total;
       i += gridDim.x * blockDim.x) {
    const float4* src; unsigned short* dst; int j;
    if (i < encN4)              { src = (const float4*)enc; dst = enc_bf;          j = i; }
    else if (i < encN4 + wN4)   { src = (const float4*)wq;  dst = w_bf;            j = i - encN4; }
    else if (i < encN4 + 2*wN4) { src = (const float4*)wk;  dst = w_bf + 131072;   j = i - encN4 - wN4; }
    else                        { src = (const float4*)wv;  dst = w_bf + 262144;   j = i - encN4 - 2*wN4; }
    float4 v = src[j];
    uint2 p;
    p.x = (unsigned)f2bf(v.x) | ((unsigned)f2bf(v.y) << 16);
    p.y = (unsigned)f2bf(v.z) | ((unsigned)f2bf(v.w) << 16);
    *(uint2*)(dst + (size_t)j * 4) = p;
  }
}

// ---------------- kernel 1: QKV projection GEMM ----------------
// M=16384 (B*T), K=1024, N=128 per group; grid.x = 128 row-blocks, grid.y = 3 (q,k,v)
// 128x128 tile, BK=64, 4 waves in 2x2. v is written TRANSPOSED: vt[b][d][s].
__global__ __launch_bounds__(256, 2) void proj_kernel(
    const unsigned short* __restrict__ enc_bf, const unsigned short* __restrict__ w_bf,
    unsigned short* __restrict__ q_bf, unsigned short* __restrict__ k_bf,
    unsigned short* __restrict__ vt_bf) {
  __shared__ __attribute__((aligned(16))) unsigned char a_tile[16384]; // [128 rows][128B] swizzled
  __shared__ __attribute__((aligned(16))) unsigned char b_tile[16384]; // [128 rows][128B] swizzled

  const int rb = blockIdx.x;
  const int gy = blockIdx.y;
  const int tid = threadIdx.x;
  const int wid = tid >> 6, lane = tid & 63;
  const int c = lane & 15, g = lane >> 4;
  const int wr = wid >> 1, wc = wid & 1;

  const unsigned short* wsrc = w_bf + gy * 131072;

  f32x4 acc[4][4];
#pragma unroll
  for (int a = 0; a < 4; ++a)
#pragma unroll
    for (int b = 0; b < 4; ++b) acc[a][b] = (f32x4){0.f, 0.f, 0.f, 0.f};

  for (int kk = 0; kk < 16; ++kk) {
    i32x4 areg[4], breg[4];
#pragma unroll
    for (int i = 0; i < 4; ++i) {
      int o = tid * 16 + i * 4096;
      int row = o >> 7, colb = o & 127;
      areg[i] = *(const i32x4*)((const char*)enc_bf +
                  (size_t)(rb * 128 + row) * 2048 + kk * 128 + colb);
      breg[i] = *(const i32x4*)((const char*)wsrc +
                  (size_t)row * 2048 + kk * 128 + colb);
    }
    __syncthreads();   // previous iteration's LDS reads done
#pragma unroll
    for (int i = 0; i < 4; ++i) {
      int o = tid * 16 + i * 4096;
      int row = o >> 7, colb = o & 127;
      int sw = colb ^ ((row & 7) << 4);
      *(i32x4*)(a_tile + row * 128 + sw) = areg[i];
      *(i32x4*)(b_tile + row * 128 + sw) = breg[i];
    }
    __syncthreads();   // staging visible
#pragma unroll
    for (int ks = 0; ks < 2; ++ks) {
      short8 af[4], bfr[4];
      int kb = ks * 64 + g * 16;
#pragma unroll
      for (int t = 0; t < 4; ++t) {
        int ar = wr * 64 + t * 16 + c;
        af[t] = *(const short8*)(a_tile + ar * 128 + (kb ^ ((ar & 7) << 4)));
        int br = wc * 64 + t * 16 + c;
        bfr[t] = *(const short8*)(b_tile + br * 128 + (kb ^ ((br & 7) << 4)));
      }
#pragma unroll
      for (int at = 0; at < 4; ++at)
#pragma unroll
        for (int bt = 0; bt < 4; ++bt)
          acc[at][bt] = __builtin_amdgcn_mfma_f32_16x16x32_bf16(
              af[at], bfr[bt], acc[at][bt], 0, 0, 0);
    }
  }

  const size_t rowbase = (size_t)rb * 128;
  if (gy < 2) {
    unsigned short* dst = (gy == 0) ? q_bf : k_bf;
#pragma unroll
    for (int at = 0; at < 4; ++at)
#pragma unroll
      for (int bt = 0; bt < 4; ++bt) {
        int r = wr * 64 + at * 16 + g * 4;
        int col = wc * 64 + bt * 16 + c;
#pragma unroll
        for (int i = 0; i < 4; ++i)
          dst[(rowbase + r + i) * 128 + col] = f2bf(acc[at][bt][i]);
      }
  } else {
    // vt[b][d][s]: the 4 acc elements are consecutive s -> 8B packed store
#pragma unroll
    for (int at = 0; at < 4; ++at)
#pragma unroll
      for (int bt = 0; bt < 4; ++bt) {
        size_t m = rowbase + wr * 64 + at * 16 + g * 4;
        int bb = (int)(m >> 11);
        int s = (int)(m & 2047);
        int d = wc * 64 + bt * 16 + c;
        uint2 p;
        p.x = (unsigned)f2bf(acc[at][bt][0]) | ((unsigned)f2bf(acc[at][bt][1]) << 16);
        p.y = (unsigned)f2bf(acc[at][bt][2]) | ((unsigned)f2bf(acc[at][bt][3]) << 16);
        *(uint2*)(vt_bf + ((size_t)bb * 128 + d) * 2048 + s) = p;
      }
  }
}

// ---------------- kernel 2: flash-style attention with s^2/||s|| normalization ----------------
// grid = 512 blocks, 256 thr (4 waves). QBLK=32 rows: waves (wr in {0,1}) x kv-split (wk in {0,1}).
// KV chunk = 64 staged in LDS; wave wk handles kv sub-range [wk*32, wk*32+32).
__global__ __launch_bounds__(256, 2) void attn_kernel(
    const unsigned short* __restrict__ q_bf, const unsigned short* __restrict__ k_bf,
    const unsigned short* __restrict__ vt_bf, float* __restrict__ out) {
  __shared__ __attribute__((aligned(16))) unsigned char k_tile[16384]; // [64 s][256B] swizzled
  __shared__ __attribute__((aligned(16))) unsigned char v_tile[16384]; // [128 d][128B] swizzled (V^T)
  __shared__ __attribute__((aligned(16))) unsigned char pt_buf[4096];  // per-wave 1KB P^T
  __shared__ float comb[2][2048];     // wk=1 partial O: [wr][(dnt*4+i)*64 + lane]
  __shared__ float rs_lds[2][16];     // wk=1 partial rowsums

  const int blk = blockIdx.x;
  int b, qt;
  if (blk < 256) { qt = 63 - (blk >> 3); b = blk & 7; }   // long items
  else           { qt = (blk - 256) >> 3; b = blk & 7; }  // short items (complementary)
  const int t0 = qt * 32;

  const int tid = threadIdx.x;
  const int wid = tid >> 6, lane = tid & 63;
  const int c = lane & 15, g = lane >> 4;
  const int wr = wid & 1, wk = wid >> 1;

  // hoist Q fragments (16 rows per wave-row-group)
  const unsigned short* qrow = q_bf + (size_t)(b * 2048 + t0 + wr * 16 + c) * 128;
  short8 qf[4];
#pragma unroll
  for (int f = 0; f < 4; ++f) qf[f] = *(const short8*)(qrow + f * 32 + g * 8);

  f32x4 accO[8];
#pragma unroll
  for (int i = 0; i < 8; ++i) accO[i] = (f32x4){0.f, 0.f, 0.f, 0.f};
  float rsum[4] = {0.f, 0.f, 0.f, 0.f};

  const char* kbase = (const char*)(k_bf + (size_t)b * 262144);
  const char* vtbase = (const char*)(vt_bf + (size_t)b * 262144);
  unsigned char* ptw = pt_buf + (wid << 10);

  const int nch = ((t0 + 31) >> 6) + 1;
  for (int ch = 0; ch < nch; ++ch) {
    const int kv0 = ch << 6;
    i32x4 kreg[4], vreg[4];
#pragma unroll
    for (int i = 0; i < 4; ++i) {
      int o = tid * 16 + i * 4096;
      { int row = o >> 8, colb = o & 255;
        kreg[i] = *(const i32x4*)(kbase + (size_t)(kv0 + row) * 256 + colb); }
      { int row = o >> 7, colb = o & 127;
        vreg[i] = *(const i32x4*)(vtbase + (size_t)row * 4096 + kv0 * 2 + colb); }
    }
    __syncthreads();
#pragma unroll
    for (int i = 0; i < 4; ++i) {
      int o = tid * 16 + i * 4096;
      { int row = o >> 8, colb = o & 255;
        *(i32x4*)(k_tile + row * 256 + (colb ^ ((row & 7) << 4))) = kreg[i]; }
      { int row = o >> 7, colb = o & 127;
        *(i32x4*)(v_tile + row * 128 + (colb ^ ((row & 7) << 4))) = vreg[i]; }
    }
    __syncthreads();

    const int mykv = kv0 + wk * 32;
    if (mykv <= t0 + 31) {
      // S = Q K^T (16 q-rows x 32 kv)
      f32x4 accS[2];
      accS[0] = (f32x4){0.f, 0.f, 0.f, 0.f};
      accS[1] = (f32x4){0.f, 0.f, 0.f, 0.f};
#pragma unroll
      for (int nt = 0; nt < 2; ++nt) {
        int srow = wk * 32 + nt * 16 + c;
#pragma unroll
        for (int ks = 0; ks < 4; ++ks) {
          short8 kf = *(const short8*)(k_tile + srow * 256 +
                        ((ks * 64 + g * 16) ^ ((srow & 7) << 4)));
          accS[nt] = __builtin_amdgcn_mfma_f32_16x16x32_bf16(qf[ks], kf, accS[nt], 0, 0, 0);
        }
      }
      // scale, causal mask, square, rowsum; write P^T (swizzled, per-wave)
      const int rowg = t0 + wr * 16 + g * 4;
#pragma unroll
      for (int nt = 0; nt < 2; ++nt) {
        int colg = mykv + nt * 16 + c;
        unsigned short us[4];
#pragma unroll
        for (int i = 0; i < 4; ++i) {
          float s = accS[nt][i] * SCALE_F;
          s = (colg <= rowg + i) ? s : 0.f;
          float p = s * s;
          rsum[i] += p;
          us[i] = f2bf(p);
        }
        int sl = nt * 16 + c;
        unsigned addr = (unsigned)(((sl << 5) | ((g * 4) << 1)) ^ (((sl >> 3) & 3) << 5));
        uint2 pw;
        pw.x = (unsigned)us[0] | ((unsigned)us[1] << 16);
        pw.y = (unsigned)us[2] | ((unsigned)us[3] << 16);
        *(uint2*)(ptw + addr) = pw;
      }
      // P fragment (A-operand): row=c (q-row), k = g*8+j
      unsigned short uu[8];
#pragma unroll
      for (int j = 0; j < 8; ++j) {
        int sl = g * 8 + j;
        unsigned addr = (unsigned)(((sl << 5) | (c << 1)) ^ (((sl >> 3) & 3) << 5));
        uu[j] = *(const unsigned short*)(ptw + addr);
      }
      short8 pf;
#pragma unroll
      for (int j = 0; j < 8; ++j) pf[j] = (short)uu[j];
      // PV: out(16 x 128) += P(16x32) * V(32x128); B-operand from V^T tile
#pragma unroll
      for (int dnt = 0; dnt < 8; ++dnt) {
        int drow = dnt * 16 + c;
        short8 vf = *(const short8*)(v_tile + drow * 128 +
                      (((wk * 32 + g * 8) * 2) ^ ((drow & 7) << 4)));
        accO[dnt] = __builtin_amdgcn_mfma_f32_16x16x32_bf16(pf, vf, accO[dnt], 0, 0, 0);
      }
    }
    __syncthreads();   // tiles fully consumed before next stage
  }

  // rowsum: reduce across the 16 column-lanes (bits 0..3 of lane)
#pragma unroll
  for (int m = 1; m < 16; m <<= 1)
#pragma unroll
    for (int i = 0; i < 4; ++i) rsum[i] += __shfl_xor(rsum[i], m, 64);

  // combine the two kv-split halves
  if (wk == 1) {
    float* cw = comb[wr];
#pragma unroll
    for (int dnt = 0; dnt < 8; ++dnt)
#pragma unroll
      for (int i = 0; i < 4; ++i) cw[(dnt * 4 + i) * 64 + lane] = accO[dnt][i];
    if (c == 0) {
#pragma unroll
      for (int i = 0; i < 4; ++i) rs_lds[wr][g * 4 + i] = rsum[i];
    }
  }
  __syncthreads();
  if (wk == 0) {
    const float* cw = comb[wr];
    float inv[4];
#pragma unroll
    for (int i = 0; i < 4; ++i) {
      float rtot = rsum[i] + rs_lds[wr][g * 4 + i];
      inv[i] = 1.0f / sqrtf(rtot);
    }
    const size_t obase = (size_t)(b * 2048 + t0 + wr * 16 + g * 4) * 128;
#pragma unroll
    for (int dnt = 0; dnt < 8; ++dnt)
#pragma unroll
      for (int i = 0; i < 4; ++i) {
        float v = (accO[dnt][i] + cw[(dnt * 4 + i) * 64 + lane]) * inv[i];
        out[obase + (size_t)i * 128 + dnt * 16 + c] = v;
      }
  }
}

extern "C" void kernel_launch(void* const* d_in, const int* in_sizes, int n_in,
                              void* d_out, int out_size, void* d_ws, size_t ws_size,
                              hipStream_t stream) {
  const float* enc = (const float*)d_in[0];
  const float* wq  = (const float*)d_in[1];
  const float* wk  = (const float*)d_in[2];
  const float* wv  = (const float*)d_in[3];
  float* out = (float*)d_out;
  char* ws = (char*)d_ws;

  unsigned short* enc_bf = (unsigned short*)ws;                       // 33,554,432 B
  unsigned short* w_bf   = (unsigned short*)(ws + 33554432);          //    786,432 B
  unsigned short* q_bf   = (unsigned short*)(ws + 34340864);          //  4,194,304 B
  unsigned short* k_bf   = (unsigned short*)(ws + 38535168);          //  4,194,304 B
  unsigned short* vt_bf  = (unsigned short*)(ws + 42729472);          //  4,194,304 B

  cvt_kernel<<<2048, 256, 0, stream>>>(enc, wq, wk, wv, enc_bf, w_bf);
  proj_kernel<<<dim3(128, 3), 256, 0, stream>>>(enc_bf, w_bf, q_bf, k_bf, vt_bf);
  attn_kernel<<<512, 256, 0, stream>>>(q_bf, k_bf, vt_bf, out);
}

// Round 5
// 160.912 us; speedup vs baseline: 1.0067x; 1.0067x over previous
//
#include <hip/hip_runtime.h>
#include <stdint.h>

typedef __attribute__((ext_vector_type(8))) short short8;
typedef __attribute__((ext_vector_type(4))) float f32x4;

#define SCALE_F 0.088388347648318447f   // 1/sqrt(128)

__device__ __forceinline__ unsigned short f2bf(float f) {
  union { float f; unsigned u; } v; v.f = f;
  unsigned r = v.u + 0x7fffu + ((v.u >> 16) & 1u);   // RNE
  return (unsigned short)(r >> 16);
}

// async global->LDS, 16B per lane. dst must be wave-uniform; HW adds lane*16.
__device__ __forceinline__ void gload_lds16(const void* g, void* l) {
  __builtin_amdgcn_global_load_lds(
      (const __attribute__((address_space(1))) unsigned int*)g,
      (__attribute__((address_space(3))) unsigned int*)l, 16, 0, 0);
}

// ---------------- kernel 0: fp32 -> bf16 convert (encodings + 3 weights) ----------------
__global__ __launch_bounds__(256) void cvt_kernel(
    const float* __restrict__ enc, const float* __restrict__ wq,
    const float* __restrict__ wk, const float* __restrict__ wv,
    unsigned short* __restrict__ enc_bf, unsigned short* __restrict__ w_bf) {
  const int encN4 = 4194304;  // 16777216/4
  const int wN4 = 32768;      // 131072/4
  int total = encN4 + 3 * wN4;
  for (int i = blockIdx.x * blockDim.x + threadIdx.x; i < total;
       i += gridDim.x * blockDim.x) {
    const float4* src; unsigned short* dst; int j;
    if (i < encN4)              { src = (const float4*)enc; dst = enc_bf;          j = i; }
    else if (i < encN4 + wN4)   { src = (const float4*)wq;  dst = w_bf;            j = i - encN4; }
    else if (i < encN4 + 2*wN4) { src = (const float4*)wk;  dst = w_bf + 131072;   j = i - encN4 - wN4; }
    else                        { src = (const float4*)wv;  dst = w_bf + 262144;   j = i - encN4 - 2*wN4; }
    float4 v = src[j];
    uint2 p;
    p.x = (unsigned)f2bf(v.x) | ((unsigned)f2bf(v.y) << 16);
    p.y = (unsigned)f2bf(v.z) | ((unsigned)f2bf(v.w) << 16);
    *(uint2*)(dst + (size_t)j * 4) = p;
  }
}

// ---------------- kernel 1: QKV projection GEMM (m97 structure + gload_lds) ----------------
// M=16384, K=1024, N=128 per gy; grid (128,3). 128x128 tile, BK=64, 4 waves 2x2.
// LDS image = swizzled layout, achieved by inverse-swizzling the per-lane SOURCE.
__global__ __launch_bounds__(256, 3) void proj_kernel(
    const unsigned short* __restrict__ enc_bf, const unsigned short* __restrict__ w_bf,
    unsigned short* __restrict__ q_bf, unsigned short* __restrict__ k_bf,
    unsigned short* __restrict__ vt_bf) {
  __shared__ __attribute__((aligned(16))) unsigned char a_tile[16384]; // [128 rows][128B] swizzled
  __shared__ __attribute__((aligned(16))) unsigned char b_tile[16384];

  const int rb = blockIdx.x;
  const int gy = blockIdx.y;
  const int tid = threadIdx.x;
  const int wid = tid >> 6, lane = tid & 63;
  const int c = lane & 15, g = lane >> 4;
  const int wr = wid >> 1, wc = wid & 1;

  const char* abase = (const char*)enc_bf + (size_t)rb * 128 * 2048;
  const char* bbase = (const char*)(w_bf + gy * 131072);

  // per-lane inverse-swizzled source geometry (constant across kk)
  // slot o = i*4096 + wid*1024 + lane*16 ; row = o>>7 ; cs = o&127 ; cg = cs ^ ((row&7)<<4)
  int srow[4], scg[4];
#pragma unroll
  for (int i = 0; i < 4; ++i) {
    int o = i * 4096 + wid * 1024 + lane * 16;
    int row = o >> 7, cs = o & 127;
    srow[i] = row;
    scg[i] = cs ^ ((row & 7) << 4);
  }

  f32x4 acc[4][4];
#pragma unroll
  for (int a = 0; a < 4; ++a)
#pragma unroll
    for (int b = 0; b < 4; ++b) acc[a][b] = (f32x4){0.f, 0.f, 0.f, 0.f};

  for (int kk = 0; kk < 16; ++kk) {
#pragma unroll
    for (int i = 0; i < 4; ++i) {
      gload_lds16(abase + (size_t)srow[i] * 2048 + kk * 128 + scg[i],
                  a_tile + i * 4096 + wid * 1024);
      gload_lds16(bbase + (size_t)srow[i] * 2048 + kk * 128 + scg[i],
                  b_tile + i * 4096 + wid * 1024);
    }
    __syncthreads();   // drain vmcnt: tile ready
#pragma unroll
    for (int ks = 0; ks < 2; ++ks) {
      short8 af[4], bfr[4];
      int kb = ks * 64 + g * 16;
#pragma unroll
      for (int t = 0; t < 4; ++t) {
        int ar = wr * 64 + t * 16 + c;
        af[t] = *(const short8*)(a_tile + ar * 128 + (kb ^ ((ar & 7) << 4)));
        int br = wc * 64 + t * 16 + c;
        bfr[t] = *(const short8*)(b_tile + br * 128 + (kb ^ ((br & 7) << 4)));
      }
#pragma unroll
      for (int at = 0; at < 4; ++at)
#pragma unroll
        for (int bt = 0; bt < 4; ++bt)
          acc[at][bt] = __builtin_amdgcn_mfma_f32_16x16x32_bf16(
              af[at], bfr[bt], acc[at][bt], 0, 0, 0);
    }
    __syncthreads();   // reads done before next staging
  }

  const size_t rowbase = (size_t)rb * 128;
  if (gy < 2) {
    unsigned short* dst = (gy == 0) ? q_bf : k_bf;
#pragma unroll
    for (int at = 0; at < 4; ++at)
#pragma unroll
      for (int bt = 0; bt < 4; ++bt) {
        int r = wr * 64 + at * 16 + g * 4;
        int col = wc * 64 + bt * 16 + c;
#pragma unroll
        for (int i = 0; i < 4; ++i)
          dst[(rowbase + r + i) * 128 + col] = f2bf(acc[at][bt][i]);
      }
  } else {
    // vt[b][d][s]: 4 acc elements are consecutive s -> 8B packed store
#pragma unroll
    for (int at = 0; at < 4; ++at)
#pragma unroll
      for (int bt = 0; bt < 4; ++bt) {
        size_t m = rowbase + wr * 64 + at * 16 + g * 4;
        int bb = (int)(m >> 11);
        int s = (int)(m & 2047);
        int d = wc * 64 + bt * 16 + c;
        uint2 p;
        p.x = (unsigned)f2bf(acc[at][bt][0]) | ((unsigned)f2bf(acc[at][bt][1]) << 16);
        p.y = (unsigned)f2bf(acc[at][bt][2]) | ((unsigned)f2bf(acc[at][bt][3]) << 16);
        *(uint2*)(vt_bf + ((size_t)bb * 128 + d) * 2048 + s) = p;
      }
  }
}

// ---------------- kernel 2: flash-style attention, s^2/||s|| normalization ----------------
// 512 blocks x 256 thr (4 waves): 2 q-row-groups x 2 kv-splits, 32 q-rows/block.
// KV chunk = 64, DOUBLE-BUFFERED via global_load_lds; ONE barrier per chunk.
__global__ __launch_bounds__(256, 2) void attn_kernel(
    const unsigned short* __restrict__ q_bf, const unsigned short* __restrict__ k_bf,
    const unsigned short* __restrict__ vt_bf, float* __restrict__ out) {
  __shared__ __attribute__((aligned(16))) unsigned char k_tile[2][16384]; // [64 s][256B] swizzled
  __shared__ __attribute__((aligned(16))) unsigned char v_tile[2][16384]; // [128 d][128B] swizzled (V^T)
  __shared__ __attribute__((aligned(16))) unsigned char pt_buf[4096];     // per-wave 1KB P^T
  // post-loop epilogue aliases dead K/V tiles:
  float* comb = (float*)&k_tile[0][0];      // [2][2048] = 16KB
  float* rs_lds = (float*)&v_tile[0][0];    // [2][16]

  const int blk = blockIdx.x;
  int b, qt;
  if (blk < 256) { qt = 63 - (blk >> 3); b = blk & 7; }   // long items first
  else           { qt = (blk - 256) >> 3; b = blk & 7; }  // complementary short items
  const int t0 = qt * 32;

  const int tid = threadIdx.x;
  const int wid = tid >> 6, lane = tid & 63;
  const int c = lane & 15, g = lane >> 4;
  const int wr = wid & 1, wk = wid >> 1;

  const unsigned short* qrow = q_bf + (size_t)(b * 2048 + t0 + wr * 16 + c) * 128;
  short8 qf[4];
#pragma unroll
  for (int f = 0; f < 4; ++f) qf[f] = *(const short8*)(qrow + f * 32 + g * 8);

  f32x4 accO[8];
#pragma unroll
  for (int i = 0; i < 8; ++i) accO[i] = (f32x4){0.f, 0.f, 0.f, 0.f};
  float rsum[4] = {0.f, 0.f, 0.f, 0.f};

  const char* kbase = (const char*)(k_bf + (size_t)b * 262144);
  const char* vtbase = (const char*)(vt_bf + (size_t)b * 262144);
  unsigned char* ptw = pt_buf + (wid << 10);

  // per-lane staging geometry
  int krow[4], kcg[4], vrow[4], vcg[4];
#pragma unroll
  for (int i = 0; i < 4; ++i) {
    int o = i * 4096 + wid * 1024 + lane * 16;
    { int row = o >> 8, cs = o & 255; krow[i] = row; kcg[i] = cs ^ ((row & 7) << 4); }
    { int row = o >> 7, cs = o & 127; vrow[i] = row; vcg[i] = cs ^ ((row & 7) << 4); }
  }

  const int nch = ((t0 + 31) >> 6) + 1;

#define STAGE(CH, BI)                                                              \
  do {                                                                             \
    const int kv0_ = (CH) << 6;                                                    \
    _Pragma("unroll")                                                              \
    for (int i = 0; i < 4; ++i) {                                                  \
      gload_lds16(kbase + (size_t)(kv0_ + krow[i]) * 256 + kcg[i],                 \
                  &k_tile[BI][i * 4096 + wid * 1024]);                             \
      gload_lds16(vtbase + (size_t)vrow[i] * 4096 + kv0_ * 2 + vcg[i],             \
                  &v_tile[BI][i * 4096 + wid * 1024]);                             \
    }                                                                              \
  } while (0)

  STAGE(0, 0);
  __syncthreads();   // chunk 0 ready

  for (int ch = 0; ch < nch; ++ch) {
    const int bi = ch & 1;
    if (ch + 1 < nch) STAGE(ch + 1, bi ^ 1);   // in flight during compute

    const int kv0 = ch << 6;
    const int mykv = kv0 + wk * 32;
    if (mykv <= t0 + 31) {
      // S = Q K^T (16 q-rows x 32 kv)
      f32x4 accS[2];
      accS[0] = (f32x4){0.f, 0.f, 0.f, 0.f};
      accS[1] = (f32x4){0.f, 0.f, 0.f, 0.f};
#pragma unroll
      for (int nt = 0; nt < 2; ++nt) {
        int srow = wk * 32 + nt * 16 + c;
#pragma unroll
        for (int ks = 0; ks < 4; ++ks) {
          short8 kf = *(const short8*)(k_tile[bi] + srow * 256 +
                        ((ks * 64 + g * 16) ^ ((srow & 7) << 4)));
          accS[nt] = __builtin_amdgcn_mfma_f32_16x16x32_bf16(qf[ks], kf, accS[nt], 0, 0, 0);
        }
      }
      // scale, causal mask, square, rowsum; write P^T (swizzled, per-wave)
      const int rowg = t0 + wr * 16 + g * 4;
#pragma unroll
      for (int nt = 0; nt < 2; ++nt) {
        int colg = mykv + nt * 16 + c;
        unsigned short us[4];
#pragma unroll
        for (int i = 0; i < 4; ++i) {
          float s = accS[nt][i] * SCALE_F;
          s = (colg <= rowg + i) ? s : 0.f;
          float p = s * s;
          rsum[i] += p;
          us[i] = f2bf(p);
        }
        int sl = nt * 16 + c;
        unsigned addr = (unsigned)(((sl << 5) | ((g * 4) << 1)) ^ (((sl >> 3) & 3) << 5));
        uint2 pw;
        pw.x = (unsigned)us[0] | ((unsigned)us[1] << 16);
        pw.y = (unsigned)us[2] | ((unsigned)us[3] << 16);
        *(uint2*)(ptw + addr) = pw;
      }
      // P fragment (A-operand): row=c (q-row), k = g*8+j
      unsigned short uu[8];
#pragma unroll
      for (int j = 0; j < 8; ++j) {
        int sl = g * 8 + j;
        unsigned addr = (unsigned)(((sl << 5) | (c << 1)) ^ (((sl >> 3) & 3) << 5));
        uu[j] = *(const unsigned short*)(ptw + addr);
      }
      short8 pf;
#pragma unroll
      for (int j = 0; j < 8; ++j) pf[j] = (short)uu[j];
      // PV: out(16 x 128) += P(16x32) * V(32x128); B-operand from V^T tile
#pragma unroll
      for (int dnt = 0; dnt < 8; ++dnt) {
        int drow = dnt * 16 + c;
        short8 vf = *(const short8*)(v_tile[bi] + drow * 128 +
                      (((wk * 32 + g * 8) * 2) ^ ((drow & 7) << 4)));
        accO[dnt] = __builtin_amdgcn_mfma_f32_16x16x32_bf16(pf, vf, accO[dnt], 0, 0, 0);
      }
    }
    __syncthreads();   // drains next-chunk loads; syncs tile reads
  }

  // rowsum: reduce across the 16 column-lanes
#pragma unroll
  for (int m = 1; m < 16; m <<= 1)
#pragma unroll
    for (int i = 0; i < 4; ++i) rsum[i] += __shfl_xor(rsum[i], m, 64);

  // combine the two kv-split halves (comb/rs alias dead K/V tiles; loop's last
  // barrier guarantees all tile reads are done)
  if (wk == 1) {
    float* cw = comb + wr * 2048;
#pragma unroll
    for (int dnt = 0; dnt < 8; ++dnt)
#pragma unroll
      for (int i = 0; i < 4; ++i) cw[(dnt * 4 + i) * 64 + lane] = accO[dnt][i];
    if (c == 0) {
#pragma unroll
      for (int i = 0; i < 4; ++i) rs_lds[wr * 16 + g * 4 + i] = rsum[i];
    }
  }
  __syncthreads();
  if (wk == 0) {
    const float* cw = comb + wr * 2048;
    float inv[4];
#pragma unroll
    for (int i = 0; i < 4; ++i) {
      float rtot = rsum[i] + rs_lds[wr * 16 + g * 4 + i];
      inv[i] = 1.0f / sqrtf(rtot);
    }
    const size_t obase = (size_t)(b * 2048 + t0 + wr * 16 + g * 4) * 128;
#pragma unroll
    for (int dnt = 0; dnt < 8; ++dnt)
#pragma unroll
      for (int i = 0; i < 4; ++i) {
        float v = (accO[dnt][i] + cw[(dnt * 4 + i) * 64 + lane]) * inv[i];
        out[obase + (size_t)i * 128 + dnt * 16 + c] = v;
      }
  }
#undef STAGE
}

extern "C" void kernel_launch(void* const* d_in, const int* in_sizes, int n_in,
                              void* d_out, int out_size, void* d_ws, size_t ws_size,
                              hipStream_t stream) {
  const float* enc = (const float*)d_in[0];
  const float* wq  = (const float*)d_in[1];
  const float* wk  = (const float*)d_in[2];
  const float* wv  = (const float*)d_in[3];
  float* out = (float*)d_out;
  char* ws = (char*)d_ws;

  unsigned short* enc_bf = (unsigned short*)ws;                       // 33,554,432 B
  unsigned short* w_bf   = (unsigned short*)(ws + 33554432);          //    786,432 B
  unsigned short* q_bf   = (unsigned short*)(ws + 34340864);          //  4,194,304 B
  unsigned short* k_bf   = (unsigned short*)(ws + 38535168);          //  4,194,304 B
  unsigned short* vt_bf  = (unsigned short*)(ws + 42729472);          //  4,194,304 B

  cvt_kernel<<<2048, 256, 0, stream>>>(enc, wq, wk, wv, enc_bf, w_bf);
  proj_kernel<<<dim3(128, 3), 256, 0, stream>>>(enc_bf, w_bf, q_bf, k_bf, vt_bf);
  attn_kernel<<<512, 256, 0, stream>>>(q_bf, k_bf, vt_bf, out);
}